// Round 8
// baseline (1091.854 us; speedup 1.0000x reference)
//
#include <hip/hip_runtime.h>
#include <hip/hip_bf16.h>
#include <math.h>

#define HIDDIM 128

typedef float f32x4 __attribute__((ext_vector_type(4)));
typedef int i32x4 __attribute__((ext_vector_type(4)));
typedef short bf16x8 __attribute__((ext_vector_type(8)));

__device__ inline float gelu_f(float x) {
  // jax.nn.gelu default approximate=True (tanh form)
  float x3 = x * x * x;
  return 0.5f * x * (1.0f + tanhf(0.7978845608028654f * (x + 0.044715f * x3)));
}

// split fp32 into bf16 hi + bf16 lo (RNE), a ~= hi + lo with ~2^-17 rel err
__device__ inline void split_bf16(float a, unsigned short& hi, unsigned short& lo) {
  unsigned u = __float_as_uint(a);
  unsigned r = (u + 0x7FFFu + ((u >> 16) & 1u)) & 0xFFFF0000u;
  hi = (unsigned short)(r >> 16);
  float rem = a - __uint_as_float(r);  // exact in fp32
  unsigned u2 = __float_as_uint(rem);
  lo = (unsigned short)((u2 + 0x7FFFu + ((u2 >> 16) & 1u)) >> 16);
}

// pair-wise split with packed output: hp = [hi(a1):hi(a0)], lp = [lo(a1):lo(a0)]
__device__ inline void split_pair(float a0, float a1, unsigned& hp, unsigned& lp) {
  unsigned u0 = __float_as_uint(a0), u1 = __float_as_uint(a1);
  unsigned r0 = (u0 + 0x7FFFu + ((u0 >> 16) & 1u)) & 0xFFFF0000u;
  unsigned r1 = (u1 + 0x7FFFu + ((u1 >> 16) & 1u)) & 0xFFFF0000u;
  hp = (r0 >> 16) | r1;
  float m0 = a0 - __uint_as_float(r0);
  float m1 = a1 - __uint_as_float(r1);
  unsigned v0 = __float_as_uint(m0), v1 = __float_as_uint(m1);
  unsigned s0 = v0 + 0x7FFFu + ((v0 >> 16) & 1u);
  unsigned s1 = (v1 + 0x7FFFu + ((v1 >> 16) & 1u)) & 0xFFFF0000u;
  lp = (s0 >> 16) | s1;
}

// split a full 32-float k-chunk fragment (2 float4) into bf16x8 hi/lo
__device__ inline void split_frag(float4 v0, float4 v1, bf16x8& ah, bf16x8& al) {
  i32x4 hv, lv;
  unsigned hp, lp;
  split_pair(v0.x, v0.y, hp, lp); hv[0] = (int)hp; lv[0] = (int)lp;
  split_pair(v0.z, v0.w, hp, lp); hv[1] = (int)hp; lv[1] = (int)lp;
  split_pair(v1.x, v1.y, hp, lp); hv[2] = (int)hp; lv[2] = (int)lp;
  split_pair(v1.z, v1.w, hp, lp); hv[3] = (int)hp; lv[3] = (int)lp;
  ah = __builtin_bit_cast(bf16x8, hv);
  al = __builtin_bit_cast(bf16x8, lv);
}

// Detect whether float tensors are fp32 (flag=1) or bf16 (flag=0).
__global__ void detect_dtype(const unsigned short* __restrict__ raw, int* __restrict__ flag) {
  __shared__ int cnt;
  if (threadIdx.x == 0) cnt = 0;
  __syncthreads();
  int c = 0;
  for (int i = threadIdx.x; i < 8192; i += 256) {
    int ex = (raw[i] >> 7) & 0xFF;
    if (ex >= 0xC0) c++;
  }
  atomicAdd(&cnt, c);
  __syncthreads();
  if (threadIdx.x == 0) flag[0] = (cnt > 64) ? 1 : 0;
}

// fused conversion of x_t and time_embed in one dispatch
__global__ void cvt_to_f32_2(const void* __restrict__ in0, const void* __restrict__ in1,
                             float* __restrict__ out0, float* __restrict__ out1,
                             int n, const int* __restrict__ flag) {
  int i = blockIdx.x * 256 + threadIdx.x;
  if (i < n) {
    out0[i] = flag[0] ? ((const float*)in0)[i]
                      : __bfloat162float(((const __hip_bfloat16*)in0)[i]);
  } else if (i < 2 * n) {
    int j = i - n;
    out1[j] = flag[0] ? ((const float*)in1)[j]
                      : __bfloat162float(((const __hip_bfloat16*)in1)[j]);
  }
}

// ---- small-param staging: biases + attn vectors (14 tensors, one dispatch) ----
#define NITEMS 14
struct StageArgs {
  const void* src[NITEMS];
  int off[NITEMS];    // dest offset in params (floats)
  int n[NITEMS];      // element count
  int blk0[NITEMS];   // first block id of this item
};
__global__ void stage_params(StageArgs a, float* __restrict__ params,
                             const int* __restrict__ flag) {
  int b = blockIdx.x;
  int it = 0;
  while (it + 1 < NITEMS && a.blk0[it + 1] <= b) ++it;
  int i = (b - a.blk0[it]) * 256 + threadIdx.x;
  if (i < a.n[it]) {
    params[a.off[it] + i] = flag[0]
        ? ((const float*)a.src[it])[i]
        : __bfloat162float(((const __hip_bfloat16*)a.src[it])[i]);
  }
}

// ---- split 12 weight matrices (row-major [K][128], fp32 or bf16 input)
// directly from d_in into col-major [128 cols][K] bf16 hi/lo arrays ----
#define NSPLIT 12
struct SplitArgs {
  const void* src[NSPLIT];
  int eoff[NSPLIT];   // element offset within src tensor (layer select)
  int soff[NSPLIT];   // dst offset in whi/wlo (ushorts)
  int K[NSPLIT];
  int blk0[NSPLIT];
};
__global__ void split_weights(SplitArgs a,
                              unsigned short* __restrict__ whi,
                              unsigned short* __restrict__ wlo,
                              const int* __restrict__ flag) {
  int b = blockIdx.x, it = 0;
  while (it + 1 < NSPLIT && a.blk0[it + 1] <= b) ++it;
  int i = (b - a.blk0[it]) * 256 + threadIdx.x;
  int K = a.K[it];
  if (i < K * 128) {
    float v = flag[0]
        ? ((const float*)a.src[it])[a.eoff[it] + i]
        : __bfloat162float(((const __hip_bfloat16*)a.src[it])[a.eoff[it] + i]);
    int k = i >> 7, col = i & 127;
    unsigned short h, lo;
    split_bf16(v, h, lo);
    int o = a.soff[it] + col * K + k;
    whi[o] = h;
    wlo[o] = lo;
  }
}

// ---------------- Unified W-stationary MFMA GEMM (high occupancy) ----------
// C[M x 128] = act( A[M x K] @ W + bias ), K = NCH*32 (NCH = 4 or 8).
// TWOSRC: k<128 rows of A from A1, k>=128 from A2 (concat layers / init).
// blockIdx.y selects matrix (W0/b0/C0 vs W1/b1/C1) for fused src/dst layers.
// Wave w covers cols w*32..+32 (CT=2) -> W fragments = 16*NCH/4 bf16x8 regs.
// Grid-stride over 32-row tiles; cross-tile 2-deep A pipeline (while chunk s
// computes, refill for s+2 -- next tile's s-(NCH-2) at the tail -- is in
// flight). No LDS, no barriers. VGPR ~116 -> 4 blocks/CU co-resident.
// Swapped MFMA operands: D = mfma(W_frag, A_frag) -> lane holds
// C[row = tb*32 + rt*16 + (l&15)][cbase + ct*16 + (l>>4)*4 .. +4] float4.
template <int NCH, int TWOSRC, int ACT>
__global__ __launch_bounds__(256, 4) void gemm_u(
    const float* __restrict__ A1, const float* __restrict__ A2,
    const unsigned short* __restrict__ Whi0, const unsigned short* __restrict__ Wlo0,
    const unsigned short* __restrict__ Whi1, const unsigned short* __restrict__ Wlo1,
    const float* __restrict__ b0, const float* __restrict__ b1,
    float* __restrict__ C0, float* __restrict__ C1, int M) {
  constexpr int KS = NCH * 32;
  const int t = threadIdx.x;
  const int w = t >> 6, l = t & 63;
  const int lr = l & 15, lk = l >> 4;
  const int mat = blockIdx.y;
  const unsigned short* whi = mat ? Whi1 : Whi0;
  const unsigned short* wlo = mat ? Wlo1 : Wlo0;
  const float* bw = mat ? b1 : b0;
  float* Cw = mat ? C1 : C0;
  const int cbase = w * 32;

  // stationary W fragments
  bf16x8 wh[2][NCH], wl[2][NCH];
#pragma unroll
  for (int ct = 0; ct < 2; ++ct)
#pragma unroll
    for (int s = 0; s < NCH; ++s) {
      size_t off = (size_t)(cbase + ct * 16 + lr) * KS + s * 32 + lk * 8;
      wh[ct][s] = *(const bf16x8*)&whi[off];
      wl[ct][s] = *(const bf16x8*)&wlo[off];
    }
  f32x4 bias[2];
#pragma unroll
  for (int ct = 0; ct < 2; ++ct)
    bias[ct] = *(const f32x4*)&bw[cbase + ct * 16 + lk * 4];

  const int ntiles = (M + 31) >> 5;
  int tb = blockIdx.x;
  int rowc[2];
#pragma unroll
  for (int rt = 0; rt < 2; ++rt) rowc[rt] = min(tb * 32 + rt * 16 + lr, M - 1);

  // prologue: issue chunks 0,1 of first tile (both from A1: NCH>=4)
  float4 rA[2][2][2];  // [buf][rt][q]
#pragma unroll
  for (int s = 0; s < 2; ++s)
#pragma unroll
    for (int rt = 0; rt < 2; ++rt) {
      const float* ap = &A1[(size_t)rowc[rt] * 128 + s * 32 + lk * 8];
      rA[s][rt][0] = *(const float4*)ap;
      rA[s][rt][1] = *(const float4*)(ap + 4);
    }

  for (; tb < ntiles; tb += gridDim.x) {
    const int tn = tb + gridDim.x;
    const bool haveNext = tn < ntiles;
    int rown[2];
#pragma unroll
    for (int rt = 0; rt < 2; ++rt)
      rown[rt] = min((haveNext ? tn : tb) * 32 + rt * 16 + lr, M - 1);

    f32x4 acc[2][2];
#pragma unroll
    for (int rt = 0; rt < 2; ++rt)
#pragma unroll
      for (int ct = 0; ct < 2; ++ct) acc[rt][ct] = (f32x4){0.f, 0.f, 0.f, 0.f};

#pragma unroll
    for (int s = 0; s < NCH; ++s) {
      const int buf = s & 1;
      bf16x8 ah[2], al[2];
#pragma unroll
      for (int rt = 0; rt < 2; ++rt)
        split_frag(rA[buf][rt][0], rA[buf][rt][1], ah[rt], al[rt]);
      // refill buf: s < NCH-2 -> this tile's chunk s+2; else next tile's s-(NCH-2)
      if (s < NCH - 2) {
        const int sn = s + 2;
        const float* Ab = (TWOSRC && sn >= 4) ? A2 : A1;
        const int krel = (sn & 3) * 32 + lk * 8;
#pragma unroll
        for (int rt = 0; rt < 2; ++rt) {
          const float* ap = &Ab[(size_t)rowc[rt] * 128 + krel];
          rA[buf][rt][0] = *(const float4*)ap;
          rA[buf][rt][1] = *(const float4*)(ap + 4);
        }
      } else if (haveNext) {
        const int sn = s - (NCH - 2);
#pragma unroll
        for (int rt = 0; rt < 2; ++rt) {
          const float* ap = &A1[(size_t)rown[rt] * 128 + sn * 32 + lk * 8];
          rA[buf][rt][0] = *(const float4*)ap;
          rA[buf][rt][1] = *(const float4*)(ap + 4);
        }
      }
#pragma unroll
      for (int rt = 0; rt < 2; ++rt)
#pragma unroll
        for (int ct = 0; ct < 2; ++ct) {
          acc[rt][ct] = __builtin_amdgcn_mfma_f32_16x16x32_bf16(wh[ct][s], ah[rt], acc[rt][ct], 0, 0, 0);
          acc[rt][ct] = __builtin_amdgcn_mfma_f32_16x16x32_bf16(wh[ct][s], al[rt], acc[rt][ct], 0, 0, 0);
          acc[rt][ct] = __builtin_amdgcn_mfma_f32_16x16x32_bf16(wl[ct][s], ah[rt], acc[rt][ct], 0, 0, 0);
          // lo*lo dropped: ~2^-18 relative, negligible
        }
    }

    // epilogue: lane stores float4 at C[row][cbase + ct*16 + lk*4]
#pragma unroll
    for (int rt = 0; rt < 2; ++rt) {
      int r = tb * 32 + rt * 16 + lr;
      if (r < M) {
        float* cp = &Cw[(size_t)r * 128 + cbase + lk * 4];
#pragma unroll
        for (int ct = 0; ct < 2; ++ct) {
          f32x4 v = acc[rt][ct] + bias[ct];
          if (ACT) {
            v[0] = gelu_f(v[0]); v[1] = gelu_f(v[1]);
            v[2] = gelu_f(v[2]); v[3] = gelu_f(v[3]);
          }
          *(f32x4*)(cp + ct * 16) = v;
        }
      }
    }
    rowc[0] = rown[0];
    rowc[1] = rown[1];
  }
}

// ---------------- CSR build ----------------
__global__ void count_deg(const int* __restrict__ dst, int* __restrict__ deg, int E) {
  int e = blockIdx.x * 256 + threadIdx.x;
  if (e < E) atomicAdd(&deg[dst[e]], 1);
}

// pass 1: per-block exclusive scan of 1024 elements + block sum
__global__ __launch_bounds__(1024) void scan_blocks(
    const int* __restrict__ deg, int* __restrict__ rowptr,
    int* __restrict__ cursor, int* __restrict__ bsum, int N) {
  __shared__ int buf[1024];
  int i = blockIdx.x * 1024 + threadIdx.x;
  int v = (i < N) ? deg[i] : 0;
  buf[threadIdx.x] = v;
  __syncthreads();
  for (int off = 1; off < 1024; off <<= 1) {
    int add = (threadIdx.x >= (unsigned)off) ? buf[threadIdx.x - off] : 0;
    __syncthreads();
    buf[threadIdx.x] += add;
    __syncthreads();
  }
  int excl = buf[threadIdx.x] - v;
  if (i < N) { rowptr[i] = excl; cursor[i] = excl; }
  if (threadIdx.x == 1023) bsum[blockIdx.x] = buf[1023];
}

// pass 2: single block exclusive-scans the block sums (nb <= 1024)
__global__ __launch_bounds__(1024) void scan_partials(int* __restrict__ bsum, int nb) {
  __shared__ int buf[1024];
  int v = (threadIdx.x < (unsigned)nb) ? bsum[threadIdx.x] : 0;
  buf[threadIdx.x] = v;
  __syncthreads();
  for (int off = 1; off < 1024; off <<= 1) {
    int add = (threadIdx.x >= (unsigned)off) ? buf[threadIdx.x - off] : 0;
    __syncthreads();
    buf[threadIdx.x] += add;
    __syncthreads();
  }
  int excl = buf[threadIdx.x] - v;
  if (threadIdx.x < (unsigned)nb) bsum[threadIdx.x] = excl;
  if (threadIdx.x == 1023) bsum[nb] = buf[1023];  // grand total
}

// pass 3: add block offsets; write rowptr[N]
__global__ void add_offsets(int* __restrict__ rowptr, int* __restrict__ cursor,
                            const int* __restrict__ bsum, int N, int nb) {
  int i = blockIdx.x * 256 + threadIdx.x;
  if (i < N) {
    int add = bsum[i >> 10];
    rowptr[i] += add;
    cursor[i] += add;
  }
  if (i == 0) rowptr[N] = bsum[nb];
}

__global__ void place_edges(const int* __restrict__ src, const int* __restrict__ dst,
                            int* __restrict__ cursor, int* __restrict__ colsrc, int E) {
  int e = blockIdx.x * 256 + threadIdx.x;
  if (e < E) {
    int pos = atomicAdd(&cursor[dst[e]], 1);
    colsrc[pos] = src[e];
  }
}

// ---------------- GATv2 aggregation (x2 edge unroll: 8 edges/wave-iter) -----
// leaky_relu(x)*a == (0.6a)*x + (0.4a)*|x|  (slope 0.2), hoisted coefficients.
__global__ __launch_bounds__(256) void gat_agg(
    const float* __restrict__ fs, const float* __restrict__ fd,
    const int* __restrict__ rowptr, const int* __restrict__ colsrc,
    const float* __restrict__ attn, const float* __restrict__ bout,
    float* __restrict__ hout, int N, int E) {
  int wv = threadIdx.x >> 6, lane = threadIdx.x & 63;
  int n = blockIdx.x * 4 + wv;
  if (n >= N) return;
  int half = lane >> 5;
  int fb = (lane & 31) * 4;
  float4 fdv = *(const float4*)&fd[(size_t)n * HIDDIM + fb];
  float b0_ = attn[fb], b1_ = attn[fb + 1], b2_ = attn[fb + 2], b3_ = attn[fb + 3];
  float a60 = 0.6f * b0_, a61 = 0.6f * b1_, a62 = 0.6f * b2_, a63 = 0.6f * b3_;
  float a40 = 0.4f * b0_, a41 = 0.4f * b1_, a42 = 0.4f * b2_, a43 = 0.4f * b3_;
  int e0 = rowptr[n], e1 = rowptr[n + 1];
  e0 = max(0, min(e0, E));
  e1 = max(e0, min(e1, E));
  float s = 0.f, ax = 0.f, ay = 0.f, az = 0.f, aw = 0.f;
  for (int c0 = e0; c0 < e1; c0 += 64) {
    int cn = min(64, e1 - c0);
    int myidx = (lane < cn) ? colsrc[c0 + lane] : 0;
    myidx = ((unsigned)myidx < (unsigned)N) ? myidx : 0;
    int iters = (cn + 7) >> 3;
    for (int it = 0; it < iters; ++it) {
      int jb = 8 * it + half;
      int sj[4];
#pragma unroll
      for (int q = 0; q < 4; ++q) sj[q] = __shfl(myidx, jb + 2 * q);
      float4 fj[4];
#pragma unroll
      for (int q = 0; q < 4; ++q)
        fj[q] = *(const float4*)&fs[(size_t)sj[q] * HIDDIM + fb];
      float pj[4];
#pragma unroll
      for (int q = 0; q < 4; ++q) {
        float x0 = fj[q].x + fdv.x, x1 = fj[q].y + fdv.y;
        float x2 = fj[q].z + fdv.z, x3 = fj[q].w + fdv.w;
        float lg = fmaf(a60, x0, a40 * fabsf(x0));
        lg = fmaf(a61, x1, fmaf(a41, fabsf(x1), lg));
        lg = fmaf(a62, x2, fmaf(a42, fabsf(x2), lg));
        lg = fmaf(a63, x3, fmaf(a43, fabsf(x3), lg));
        lg += __shfl_xor(lg, 1); lg += __shfl_xor(lg, 2); lg += __shfl_xor(lg, 4);
        lg = fminf(lg, 60.f);
        pj[q] = (jb + 2 * q < cn) ? __expf(lg) : 0.f;
      }
#pragma unroll
      for (int q = 0; q < 4; ++q) {
        s += pj[q];
        ax = fmaf(pj[q], fj[q].x, ax);
        ay = fmaf(pj[q], fj[q].y, ay);
        az = fmaf(pj[q], fj[q].z, az);
        aw = fmaf(pj[q], fj[q].w, aw);
      }
    }
  }
  s += __shfl_xor(s, 32);
  ax += __shfl_xor(ax, 32); ay += __shfl_xor(ay, 32);
  az += __shfl_xor(az, 32); aw += __shfl_xor(aw, 32);
  if (half == 0) {
    float inv = 1.f / (s + 1e-9f);
    float o0 = gelu_f(fmaf(ax, inv, bout[fb]));
    float o1 = gelu_f(fmaf(ay, inv, bout[fb + 1]));
    float o2 = gelu_f(fmaf(az, inv, bout[fb + 2]));
    float o3 = gelu_f(fmaf(aw, inv, bout[fb + 3]));
    *(float4*)&hout[(size_t)n * HIDDIM + fb] = make_float4(o0, o1, o2, o3);
  }
}

__global__ void store_out(const float* __restrict__ og, const float* __restrict__ h,
                          void* __restrict__ dout, int n, const int* __restrict__ flag) {
  int i = blockIdx.x * 256 + threadIdx.x;
  if (i >= n) return;
  if (flag[0]) {
    ((float*)dout)[i] = og[i];
    ((float*)dout)[n + i] = h[i];
  } else {
    ((__hip_bfloat16*)dout)[i] = __float2bfloat16(og[i]);
    ((__hip_bfloat16*)dout)[n + i] = __float2bfloat16(h[i]);
  }
}

// packed fp32 small-param offsets (floats)
#define PB_INIT    0
#define PBSRC_DOWN 128
#define PBDST_DOWN 384
#define PATTN_DOWN 640
#define PBOUT_DOWN 896
#define PBSRC_MID  1152
#define PBDST_MID  1280
#define PATTN_MID  1408
#define PBOUT_MID  1536
#define PBSRC_UP   1664
#define PBDST_UP   1920
#define PATTN_UP   2176
#define PBOUT_UP   2432
#define PB_FIN     2688
#define PARAMS_TOTAL 2816

// split-weight offsets (ushorts, col-major [128][K] per matrix)
#define SP_W_INIT    0        // K=256
#define SP_WSRC_D0   32768    // K=128
#define SP_WSRC_D1   49152
#define SP_WDST_D0   65536
#define SP_WDST_D1   81920
#define SP_WSRC_MID  98304
#define SP_WDST_MID  114688
#define SP_WSRC_U0   131072   // K=256
#define SP_WSRC_U1   163840
#define SP_WDST_U0   196608
#define SP_WDST_U1   229376
#define SP_W_FIN     262144   // K=128
#define SPLIT_TOTAL  278528

extern "C" void kernel_launch(void* const* d_in, const int* in_sizes, int n_in,
                              void* d_out, int out_size, void* d_ws, size_t ws_size,
                              hipStream_t stream) {
  const int N = in_sizes[1] / HIDDIM;
  const int E = in_sizes[2];
  const int* src = (const int*)d_in[2];
  const int* dst = (const int*)d_in[3];

  char* p = (char*)d_ws;
  auto carve = [&](size_t bytes) {
    void* r = (void*)p;
    p += (bytes + 255) & ~(size_t)255;
    return r;
  };
  int* flag     = (int*)carve(256);
  float* params = (float*)carve((size_t)PARAMS_TOTAL * 4);
  unsigned short* whi = (unsigned short*)carve((size_t)SPLIT_TOTAL * 2);
  unsigned short* wlo = (unsigned short*)carve((size_t)SPLIT_TOTAL * 2);
  int* deg      = (int*)carve((size_t)N * 4);
  int* rowptr   = (int*)carve((size_t)(N + 1) * 4);
  int* cursor   = (int*)carve((size_t)N * 4);
  int* bsum     = (int*)carve(1032 * 4);
  int* colsrc   = (int*)carve((size_t)E * 4);
  float* hA     = (float*)carve((size_t)N * HIDDIM * 4);
  float* hB     = (float*)carve((size_t)N * HIDDIM * 4);
  float* hC     = (float*)carve((size_t)N * HIDDIM * 4);
  float* fs     = (float*)carve((size_t)N * HIDDIM * 4);
  float* fd     = (float*)carve((size_t)N * HIDDIM * 4);

  // 1. dtype flag
  detect_dtype<<<1, 256, 0, stream>>>((const unsigned short*)d_in[0], flag);

  // 2. stage small params (biases + attn) in one dispatch
  static const int idx[NITEMS] = {5, 7, 9, 10, 11, 13, 15, 16, 17, 19, 21, 22, 23, 25};
  static const int off[NITEMS] = {
    PB_INIT, PBSRC_DOWN, PBDST_DOWN, PATTN_DOWN, PBOUT_DOWN,
    PBSRC_MID, PBDST_MID, PATTN_MID, PBOUT_MID,
    PBSRC_UP, PBDST_UP, PATTN_UP, PBOUT_UP, PB_FIN};
  static const int cnt[NITEMS] = {
    128, 256, 256, 256, 256, 128, 128, 128, 128, 256, 256, 256, 256, 128};
  StageArgs sa;
  int nb = 0;
  for (int i = 0; i < NITEMS; ++i) {
    sa.src[i] = d_in[idx[i]];
    sa.off[i] = off[i];
    sa.n[i] = cnt[i];
    sa.blk0[i] = nb;
    nb += (cnt[i] + 255) / 256;
  }
  stage_params<<<nb, 256, 0, stream>>>(sa, params, flag);

  // 2b. split weights (direct from inputs) into col-major bf16 hi/lo
  static const int widx[NSPLIT]  = {4, 6, 6, 8, 8, 12, 14, 18, 18, 20, 20, 24};
  static const int weoff[NSPLIT] = {0, 0, 16384, 0, 16384, 0, 0, 0, 32768, 0, 32768, 0};
  static const int wsoff[NSPLIT] = {
    SP_W_INIT, SP_WSRC_D0, SP_WSRC_D1, SP_WDST_D0, SP_WDST_D1,
    SP_WSRC_MID, SP_WDST_MID, SP_WSRC_U0, SP_WSRC_U1, SP_WDST_U0, SP_WDST_U1,
    SP_W_FIN};
  static const int wK[NSPLIT] = {256, 128, 128, 128, 128, 128, 128, 256, 256, 256, 256, 128};
  SplitArgs spa;
  int snb = 0;
  for (int i = 0; i < NSPLIT; ++i) {
    spa.src[i] = d_in[widx[i]];
    spa.eoff[i] = weoff[i];
    spa.soff[i] = wsoff[i];
    spa.K[i] = wK[i];
    spa.blk0[i] = snb;
    snb += (wK[i] * 128 + 255) / 256;
  }
  split_weights<<<snb, 256, 0, stream>>>(spa, whi, wlo, flag);

  // stage x_t, time_embed into fs/fd (consumed by init GEMM before reuse)
  float* xc = fs;
  float* tc = fd;
  cvt_to_f32_2<<<(2 * N * HIDDIM + 255) / 256, 256, 0, stream>>>(
      d_in[0], d_in[1], xc, tc, N * HIDDIM, flag);

  // 3. CSR by dst (multi-block 3-pass scan)
  hipMemsetAsync(deg, 0, (size_t)N * 4, stream);
  count_deg<<<(E + 255) / 256, 256, 0, stream>>>(dst, deg, E);
  int nsb = (N + 1023) / 1024;
  scan_blocks<<<nsb, 1024, 0, stream>>>(deg, rowptr, cursor, bsum, N);
  scan_partials<<<1, 1024, 0, stream>>>(bsum, nsb);
  add_offsets<<<(N + 255) / 256, 256, 0, stream>>>(rowptr, cursor, bsum, N, nsb);
  place_edges<<<(E + 255) / 256, 256, 0, stream>>>(src, dst, cursor, colsrc, E);

  const int nt32 = (N + 31) >> 5;
  // 1024 resident blocks (4/CU): x=512 when y=2, x=1024 when y=1
  dim3 gwy2((unsigned)min(512, nt32), 2);
  dim3 gwy1((unsigned)min(1024, nt32), 1);
  dim3 ga((N + 3) / 4);
  const float* P = params;
  const unsigned short* nh = nullptr;

  // init: hA = gelu([x_t | time_embed] @ W_init + b_init)  (hA kept: skip0)
  gemm_u<8, 1, 1><<<gwy1, 256, 0, stream>>>(
      xc, tc, whi + SP_W_INIT, wlo + SP_W_INIT, nh, nh,
      P + PB_INIT, nullptr, hA, nullptr, N);

  // down 0: hA -> hB   (hB kept: skip1)
  gemm_u<4, 0, 0><<<gwy2, 256, 0, stream>>>(
      hA, nullptr, whi + SP_WSRC_D0, wlo + SP_WSRC_D0, whi + SP_WDST_D0, wlo + SP_WDST_D0,
      P + PBSRC_DOWN, P + PBDST_DOWN, fs, fd, N);
  gat_agg<<<ga, 256, 0, stream>>>(fs, fd, rowptr, colsrc,
                                  P + PATTN_DOWN, P + PBOUT_DOWN, hB, N, E);
  // down 1: hB -> hC
  gemm_u<4, 0, 0><<<gwy2, 256, 0, stream>>>(
      hB, nullptr, whi + SP_WSRC_D1, wlo + SP_WSRC_D1, whi + SP_WDST_D1, wlo + SP_WDST_D1,
      P + PBSRC_DOWN + 128, P + PBDST_DOWN + 128, fs, fd, N);
  gat_agg<<<ga, 256, 0, stream>>>(fs, fd, rowptr, colsrc,
                                  P + PATTN_DOWN + 128, P + PBOUT_DOWN + 128, hC, N, E);
  // mid: hC -> hC
  gemm_u<4, 0, 0><<<gwy2, 256, 0, stream>>>(
      hC, nullptr, whi + SP_WSRC_MID, wlo + SP_WSRC_MID, whi + SP_WDST_MID, wlo + SP_WDST_MID,
      P + PBSRC_MID, P + PBDST_MID, fs, fd, N);
  gat_agg<<<ga, 256, 0, stream>>>(fs, fd, rowptr, colsrc,
                                  P + PATTN_MID, P + PBOUT_MID, hC, N, E);
  // up 0: concat([hC, hB]) -> hC   (single dispatch, K=256, y selects src/dst)
  gemm_u<8, 1, 0><<<gwy2, 256, 0, stream>>>(
      hC, hB, whi + SP_WSRC_U0, wlo + SP_WSRC_U0, whi + SP_WDST_U0, wlo + SP_WDST_U0,
      P + PBSRC_UP, P + PBDST_UP, fs, fd, N);
  gat_agg<<<ga, 256, 0, stream>>>(fs, fd, rowptr, colsrc,
                                  P + PATTN_UP, P + PBOUT_UP, hC, N, E);
  // up 1: concat([hC, hA]) -> hC
  gemm_u<8, 1, 0><<<gwy2, 256, 0, stream>>>(
      hC, hA, whi + SP_WSRC_U1, wlo + SP_WSRC_U1, whi + SP_WDST_U1, wlo + SP_WDST_U1,
      P + PBSRC_UP + 128, P + PBDST_UP + 128, fs, fd, N);
  gat_agg<<<ga, 256, 0, stream>>>(fs, fd, rowptr, colsrc,
                                  P + PATTN_UP + 128, P + PBOUT_UP + 128, hC, N, E);

  // fin: out = hC @ W_fin + b_fin -> hB (dead), then dtype-aware store
  float* outg = hB;
  gemm_u<4, 0, 0><<<gwy1, 256, 0, stream>>>(
      hC, nullptr, whi + SP_W_FIN, wlo + SP_W_FIN, nh, nh,
      P + PB_FIN, nullptr, outg, nullptr, N);
  store_out<<<(N * HIDDIM + 255) / 256, 256, 0, stream>>>(outg, hC, d_out, N * HIDDIM, flag);
}

// Round 9
// 997.155 us; speedup vs baseline: 1.0950x; 1.0950x over previous
//
#include <hip/hip_runtime.h>
#include <hip/hip_bf16.h>
#include <math.h>

#define HIDDIM 128

typedef float f32x4 __attribute__((ext_vector_type(4)));
typedef int i32x4 __attribute__((ext_vector_type(4)));
typedef short bf16x8 __attribute__((ext_vector_type(8)));

__device__ inline float gelu_f(float x) {
  // jax.nn.gelu default approximate=True (tanh form)
  float x3 = x * x * x;
  return 0.5f * x * (1.0f + tanhf(0.7978845608028654f * (x + 0.044715f * x3)));
}

// split fp32 into bf16 hi + bf16 lo (RNE), a ~= hi + lo with ~2^-17 rel err
__device__ inline void split_bf16(float a, unsigned short& hi, unsigned short& lo) {
  unsigned u = __float_as_uint(a);
  unsigned r = (u + 0x7FFFu + ((u >> 16) & 1u)) & 0xFFFF0000u;
  hi = (unsigned short)(r >> 16);
  float rem = a - __uint_as_float(r);  // exact in fp32
  unsigned u2 = __float_as_uint(rem);
  lo = (unsigned short)((u2 + 0x7FFFu + ((u2 >> 16) & 1u)) >> 16);
}

// pair-wise split with packed output: hp = [hi(a1):hi(a0)], lp = [lo(a1):lo(a0)]
__device__ inline void split_pair(float a0, float a1, unsigned& hp, unsigned& lp) {
  unsigned u0 = __float_as_uint(a0), u1 = __float_as_uint(a1);
  unsigned r0 = (u0 + 0x7FFFu + ((u0 >> 16) & 1u)) & 0xFFFF0000u;
  unsigned r1 = (u1 + 0x7FFFu + ((u1 >> 16) & 1u)) & 0xFFFF0000u;
  hp = (r0 >> 16) | r1;
  float m0 = a0 - __uint_as_float(r0);
  float m1 = a1 - __uint_as_float(r1);
  unsigned v0 = __float_as_uint(m0), v1 = __float_as_uint(m1);
  unsigned s0 = v0 + 0x7FFFu + ((v0 >> 16) & 1u);
  unsigned s1 = (v1 + 0x7FFFu + ((v1 >> 16) & 1u)) & 0xFFFF0000u;
  lp = (s0 >> 16) | s1;
}

// split a full 32-float k-chunk fragment (2 float4) into bf16x8 hi/lo
__device__ inline void split_frag(float4 v0, float4 v1, bf16x8& ah, bf16x8& al) {
  i32x4 hv, lv;
  unsigned hp, lp;
  split_pair(v0.x, v0.y, hp, lp); hv[0] = (int)hp; lv[0] = (int)lp;
  split_pair(v0.z, v0.w, hp, lp); hv[1] = (int)hp; lv[1] = (int)lp;
  split_pair(v1.x, v1.y, hp, lp); hv[2] = (int)hp; lv[2] = (int)lp;
  split_pair(v1.z, v1.w, hp, lp); hv[3] = (int)hp; lv[3] = (int)lp;
  ah = __builtin_bit_cast(bf16x8, hv);
  al = __builtin_bit_cast(bf16x8, lv);
}

// Detect whether float tensors are fp32 (flag=1) or bf16 (flag=0).
__global__ void detect_dtype(const unsigned short* __restrict__ raw, int* __restrict__ flag) {
  __shared__ int cnt;
  if (threadIdx.x == 0) cnt = 0;
  __syncthreads();
  int c = 0;
  for (int i = threadIdx.x; i < 8192; i += 256) {
    int ex = (raw[i] >> 7) & 0xFF;
    if (ex >= 0xC0) c++;
  }
  atomicAdd(&cnt, c);
  __syncthreads();
  if (threadIdx.x == 0) flag[0] = (cnt > 64) ? 1 : 0;
}

// fused conversion of x_t and time_embed in one dispatch
__global__ void cvt_to_f32_2(const void* __restrict__ in0, const void* __restrict__ in1,
                             float* __restrict__ out0, float* __restrict__ out1,
                             int n, const int* __restrict__ flag) {
  int i = blockIdx.x * 256 + threadIdx.x;
  if (i < n) {
    out0[i] = flag[0] ? ((const float*)in0)[i]
                      : __bfloat162float(((const __hip_bfloat16*)in0)[i]);
  } else if (i < 2 * n) {
    int j = i - n;
    out1[j] = flag[0] ? ((const float*)in1)[j]
                      : __bfloat162float(((const __hip_bfloat16*)in1)[j]);
  }
}

// ---- small-param staging: biases + attn vectors (14 tensors, one dispatch) ----
#define NITEMS 14
struct StageArgs {
  const void* src[NITEMS];
  int off[NITEMS];    // dest offset in params (floats)
  int n[NITEMS];      // element count
  int blk0[NITEMS];   // first block id of this item
};
__global__ void stage_params(StageArgs a, float* __restrict__ params,
                             const int* __restrict__ flag) {
  int b = blockIdx.x;
  int it = 0;
  while (it + 1 < NITEMS && a.blk0[it + 1] <= b) ++it;
  int i = (b - a.blk0[it]) * 256 + threadIdx.x;
  if (i < a.n[it]) {
    params[a.off[it] + i] = flag[0]
        ? ((const float*)a.src[it])[i]
        : __bfloat162float(((const __hip_bfloat16*)a.src[it])[i]);
  }
}

// ---- split 12 weight matrices (row-major [K][128], fp32 or bf16 input)
// directly from d_in into col-major [128 cols][K] bf16 hi/lo arrays ----
#define NSPLIT 12
struct SplitArgs {
  const void* src[NSPLIT];
  int eoff[NSPLIT];   // element offset within src tensor (layer select)
  int soff[NSPLIT];   // dst offset in whi/wlo (ushorts)
  int K[NSPLIT];
  int blk0[NSPLIT];
};
__global__ void split_weights(SplitArgs a,
                              unsigned short* __restrict__ whi,
                              unsigned short* __restrict__ wlo,
                              const int* __restrict__ flag) {
  int b = blockIdx.x, it = 0;
  while (it + 1 < NSPLIT && a.blk0[it + 1] <= b) ++it;
  int i = (b - a.blk0[it]) * 256 + threadIdx.x;
  int K = a.K[it];
  if (i < K * 128) {
    float v = flag[0]
        ? ((const float*)a.src[it])[a.eoff[it] + i]
        : __bfloat162float(((const __hip_bfloat16*)a.src[it])[a.eoff[it] + i]);
    int k = i >> 7, col = i & 127;
    unsigned short h, lo;
    split_bf16(v, h, lo);
    int o = a.soff[it] + col * K + k;
    whi[o] = h;
    wlo[o] = lo;
  }
}

// ---------------- Unified W-stationary MFMA GEMM ----------
// C[M x 128] = act( A[M x K] @ W + bias ), K = NCH*32 (NCH = 4 or 8).
// TWOSRC: k<128 rows of A from A1, k>=128 from A2 (concat layers / init).
// blockIdx.y selects matrix (W0/b0/C0 vs W1/b1/C1) for fused src/dst layers.
// Wave w covers cols w*32..+32 (CT=2). Grid-stride over 32-row tiles;
// cross-tile 2-deep A pipeline. No LDS, no barriers.
// __launch_bounds__(256,3): VGPR cap ~170 -- kernel's natural ~116 (round-7
// measured) fits WITHOUT scratch spill (round-8's bound=4 / cap=128 spilled
// the W fragments: FETCH 209MB vs 51MB real).
// Swapped MFMA operands: D = mfma(W_frag, A_frag) -> lane holds
// C[row = tb*32 + rt*16 + (l&15)][cbase + ct*16 + (l>>4)*4 .. +4] float4.
template <int NCH, int TWOSRC, int ACT>
__global__ __launch_bounds__(256, 3) void gemm_u(
    const float* __restrict__ A1, const float* __restrict__ A2,
    const unsigned short* __restrict__ Whi0, const unsigned short* __restrict__ Wlo0,
    const unsigned short* __restrict__ Whi1, const unsigned short* __restrict__ Wlo1,
    const float* __restrict__ b0, const float* __restrict__ b1,
    float* __restrict__ C0, float* __restrict__ C1, int M) {
  constexpr int KS = NCH * 32;
  const int t = threadIdx.x;
  const int w = t >> 6, l = t & 63;
  const int lr = l & 15, lk = l >> 4;
  const int mat = blockIdx.y;
  const unsigned short* whi = mat ? Whi1 : Whi0;
  const unsigned short* wlo = mat ? Wlo1 : Wlo0;
  const float* bw = mat ? b1 : b0;
  float* Cw = mat ? C1 : C0;
  const int cbase = w * 32;

  // stationary W fragments (compiler may re-materialize some from L2 -- fine)
  bf16x8 wh[2][NCH], wl[2][NCH];
#pragma unroll
  for (int ct = 0; ct < 2; ++ct)
#pragma unroll
    for (int s = 0; s < NCH; ++s) {
      size_t off = (size_t)(cbase + ct * 16 + lr) * KS + s * 32 + lk * 8;
      wh[ct][s] = *(const bf16x8*)&whi[off];
      wl[ct][s] = *(const bf16x8*)&wlo[off];
    }
  f32x4 bias[2];
#pragma unroll
  for (int ct = 0; ct < 2; ++ct)
    bias[ct] = *(const f32x4*)&bw[cbase + ct * 16 + lk * 4];

  const int ntiles = (M + 31) >> 5;
  int tb = blockIdx.x;
  int rowc[2];
#pragma unroll
  for (int rt = 0; rt < 2; ++rt) rowc[rt] = min(tb * 32 + rt * 16 + lr, M - 1);

  // prologue: issue chunks 0,1 of first tile (both from A1: NCH>=4)
  float4 rA[2][2][2];  // [buf][rt][q]
#pragma unroll
  for (int s = 0; s < 2; ++s)
#pragma unroll
    for (int rt = 0; rt < 2; ++rt) {
      const float* ap = &A1[(size_t)rowc[rt] * 128 + s * 32 + lk * 8];
      rA[s][rt][0] = *(const float4*)ap;
      rA[s][rt][1] = *(const float4*)(ap + 4);
    }

  for (; tb < ntiles; tb += gridDim.x) {
    const int tn = tb + gridDim.x;
    const bool haveNext = tn < ntiles;
    int rown[2];
#pragma unroll
    for (int rt = 0; rt < 2; ++rt)
      rown[rt] = min((haveNext ? tn : tb) * 32 + rt * 16 + lr, M - 1);

    f32x4 acc[2][2];
#pragma unroll
    for (int rt = 0; rt < 2; ++rt)
#pragma unroll
      for (int ct = 0; ct < 2; ++ct) acc[rt][ct] = (f32x4){0.f, 0.f, 0.f, 0.f};

#pragma unroll
    for (int s = 0; s < NCH; ++s) {
      const int buf = s & 1;
      bf16x8 ah[2], al[2];
#pragma unroll
      for (int rt = 0; rt < 2; ++rt)
        split_frag(rA[buf][rt][0], rA[buf][rt][1], ah[rt], al[rt]);
      // refill buf: s < NCH-2 -> this tile's chunk s+2; else next tile's s-(NCH-2)
      if (s < NCH - 2) {
        const int sn = s + 2;
        const float* Ab = (TWOSRC && sn >= 4) ? A2 : A1;
        const int krel = (sn & 3) * 32 + lk * 8;
#pragma unroll
        for (int rt = 0; rt < 2; ++rt) {
          const float* ap = &Ab[(size_t)rowc[rt] * 128 + krel];
          rA[buf][rt][0] = *(const float4*)ap;
          rA[buf][rt][1] = *(const float4*)(ap + 4);
        }
      } else if (haveNext) {
        const int sn = s - (NCH - 2);
#pragma unroll
        for (int rt = 0; rt < 2; ++rt) {
          const float* ap = &A1[(size_t)rown[rt] * 128 + sn * 32 + lk * 8];
          rA[buf][rt][0] = *(const float4*)ap;
          rA[buf][rt][1] = *(const float4*)(ap + 4);
        }
      }
#pragma unroll
      for (int rt = 0; rt < 2; ++rt)
#pragma unroll
        for (int ct = 0; ct < 2; ++ct) {
          acc[rt][ct] = __builtin_amdgcn_mfma_f32_16x16x32_bf16(wh[ct][s], ah[rt], acc[rt][ct], 0, 0, 0);
          acc[rt][ct] = __builtin_amdgcn_mfma_f32_16x16x32_bf16(wh[ct][s], al[rt], acc[rt][ct], 0, 0, 0);
          acc[rt][ct] = __builtin_amdgcn_mfma_f32_16x16x32_bf16(wl[ct][s], ah[rt], acc[rt][ct], 0, 0, 0);
          // lo*lo dropped: ~2^-18 relative, negligible
        }
    }

    // epilogue: lane stores float4 at C[row][cbase + ct*16 + lk*4]
#pragma unroll
    for (int rt = 0; rt < 2; ++rt) {
      int r = tb * 32 + rt * 16 + lr;
      if (r < M) {
        float* cp = &Cw[(size_t)r * 128 + cbase + lk * 4];
#pragma unroll
        for (int ct = 0; ct < 2; ++ct) {
          f32x4 v = acc[rt][ct] + bias[ct];
          if (ACT) {
            v[0] = gelu_f(v[0]); v[1] = gelu_f(v[1]);
            v[2] = gelu_f(v[2]); v[3] = gelu_f(v[3]);
          }
          *(f32x4*)(cp + ct * 16) = v;
        }
      }
    }
    rowc[0] = rown[0];
    rowc[1] = rown[1];
  }
}

// ---------------- CSR build ----------------
__global__ void count_deg(const int* __restrict__ dst, int* __restrict__ deg, int E) {
  int e = blockIdx.x * 256 + threadIdx.x;
  if (e < E) atomicAdd(&deg[dst[e]], 1);
}

// pass 1: per-block exclusive scan of 1024 elements + block sum
__global__ __launch_bounds__(1024) void scan_blocks(
    const int* __restrict__ deg, int* __restrict__ rowptr,
    int* __restrict__ cursor, int* __restrict__ bsum, int N) {
  __shared__ int buf[1024];
  int i = blockIdx.x * 1024 + threadIdx.x;
  int v = (i < N) ? deg[i] : 0;
  buf[threadIdx.x] = v;
  __syncthreads();
  for (int off = 1; off < 1024; off <<= 1) {
    int add = (threadIdx.x >= (unsigned)off) ? buf[threadIdx.x - off] : 0;
    __syncthreads();
    buf[threadIdx.x] += add;
    __syncthreads();
  }
  int excl = buf[threadIdx.x] - v;
  if (i < N) { rowptr[i] = excl; cursor[i] = excl; }
  if (threadIdx.x == 1023) bsum[blockIdx.x] = buf[1023];
}

// pass 2: single block exclusive-scans the block sums (nb <= 1024)
__global__ __launch_bounds__(1024) void scan_partials(int* __restrict__ bsum, int nb) {
  __shared__ int buf[1024];
  int v = (threadIdx.x < (unsigned)nb) ? bsum[threadIdx.x] : 0;
  buf[threadIdx.x] = v;
  __syncthreads();
  for (int off = 1; off < 1024; off <<= 1) {
    int add = (threadIdx.x >= (unsigned)off) ? buf[threadIdx.x - off] : 0;
    __syncthreads();
    buf[threadIdx.x] += add;
    __syncthreads();
  }
  int excl = buf[threadIdx.x] - v;
  if (threadIdx.x < (unsigned)nb) bsum[threadIdx.x] = excl;
  if (threadIdx.x == 1023) bsum[nb] = buf[1023];  // grand total
}

// pass 3: add block offsets; write rowptr[N]
__global__ void add_offsets(int* __restrict__ rowptr, int* __restrict__ cursor,
                            const int* __restrict__ bsum, int N, int nb) {
  int i = blockIdx.x * 256 + threadIdx.x;
  if (i < N) {
    int add = bsum[i >> 10];
    rowptr[i] += add;
    cursor[i] += add;
  }
  if (i == 0) rowptr[N] = bsum[nb];
}

__global__ void place_edges(const int* __restrict__ src, const int* __restrict__ dst,
                            int* __restrict__ cursor, int* __restrict__ colsrc, int E) {
  int e = blockIdx.x * 256 + threadIdx.x;
  if (e < E) {
    int pos = atomicAdd(&cursor[dst[e]], 1);
    colsrc[pos] = src[e];
  }
}

// ---------------- GATv2 aggregation (x2 edge unroll: 8 edges/wave-iter) -----
// leaky_relu(x)*a == (0.6a)*x + (0.4a)*|x|  (slope 0.2), hoisted coefficients.
__global__ __launch_bounds__(256) void gat_agg(
    const float* __restrict__ fs, const float* __restrict__ fd,
    const int* __restrict__ rowptr, const int* __restrict__ colsrc,
    const float* __restrict__ attn, const float* __restrict__ bout,
    float* __restrict__ hout, int N, int E) {
  int wv = threadIdx.x >> 6, lane = threadIdx.x & 63;
  int n = blockIdx.x * 4 + wv;
  if (n >= N) return;
  int half = lane >> 5;
  int fb = (lane & 31) * 4;
  float4 fdv = *(const float4*)&fd[(size_t)n * HIDDIM + fb];
  float b0_ = attn[fb], b1_ = attn[fb + 1], b2_ = attn[fb + 2], b3_ = attn[fb + 3];
  float a60 = 0.6f * b0_, a61 = 0.6f * b1_, a62 = 0.6f * b2_, a63 = 0.6f * b3_;
  float a40 = 0.4f * b0_, a41 = 0.4f * b1_, a42 = 0.4f * b2_, a43 = 0.4f * b3_;
  int e0 = rowptr[n], e1 = rowptr[n + 1];
  e0 = max(0, min(e0, E));
  e1 = max(e0, min(e1, E));
  float s = 0.f, ax = 0.f, ay = 0.f, az = 0.f, aw = 0.f;
  for (int c0 = e0; c0 < e1; c0 += 64) {
    int cn = min(64, e1 - c0);
    int myidx = (lane < cn) ? colsrc[c0 + lane] : 0;
    myidx = ((unsigned)myidx < (unsigned)N) ? myidx : 0;
    int iters = (cn + 7) >> 3;
    for (int it = 0; it < iters; ++it) {
      int jb = 8 * it + half;
      int sj[4];
#pragma unroll
      for (int q = 0; q < 4; ++q) sj[q] = __shfl(myidx, jb + 2 * q);
      float4 fj[4];
#pragma unroll
      for (int q = 0; q < 4; ++q)
        fj[q] = *(const float4*)&fs[(size_t)sj[q] * HIDDIM + fb];
      float pj[4];
#pragma unroll
      for (int q = 0; q < 4; ++q) {
        float x0 = fj[q].x + fdv.x, x1 = fj[q].y + fdv.y;
        float x2 = fj[q].z + fdv.z, x3 = fj[q].w + fdv.w;
        float lg = fmaf(a60, x0, a40 * fabsf(x0));
        lg = fmaf(a61, x1, fmaf(a41, fabsf(x1), lg));
        lg = fmaf(a62, x2, fmaf(a42, fabsf(x2), lg));
        lg = fmaf(a63, x3, fmaf(a43, fabsf(x3), lg));
        lg += __shfl_xor(lg, 1); lg += __shfl_xor(lg, 2); lg += __shfl_xor(lg, 4);
        lg = fminf(lg, 60.f);
        pj[q] = (jb + 2 * q < cn) ? __expf(lg) : 0.f;
      }
#pragma unroll
      for (int q = 0; q < 4; ++q) {
        s += pj[q];
        ax = fmaf(pj[q], fj[q].x, ax);
        ay = fmaf(pj[q], fj[q].y, ay);
        az = fmaf(pj[q], fj[q].z, az);
        aw = fmaf(pj[q], fj[q].w, aw);
      }
    }
  }
  s += __shfl_xor(s, 32);
  ax += __shfl_xor(ax, 32); ay += __shfl_xor(ay, 32);
  az += __shfl_xor(az, 32); aw += __shfl_xor(aw, 32);
  if (half == 0) {
    float inv = 1.f / (s + 1e-9f);
    float o0 = gelu_f(fmaf(ax, inv, bout[fb]));
    float o1 = gelu_f(fmaf(ay, inv, bout[fb + 1]));
    float o2 = gelu_f(fmaf(az, inv, bout[fb + 2]));
    float o3 = gelu_f(fmaf(aw, inv, bout[fb + 3]));
    *(float4*)&hout[(size_t)n * HIDDIM + fb] = make_float4(o0, o1, o2, o3);
  }
}

__global__ void store_out(const float* __restrict__ og, const float* __restrict__ h,
                          void* __restrict__ dout, int n, const int* __restrict__ flag) {
  int i = blockIdx.x * 256 + threadIdx.x;
  if (i >= n) return;
  if (flag[0]) {
    ((float*)dout)[i] = og[i];
    ((float*)dout)[n + i] = h[i];
  } else {
    ((__hip_bfloat16*)dout)[i] = __float2bfloat16(og[i]);
    ((__hip_bfloat16*)dout)[n + i] = __float2bfloat16(h[i]);
  }
}

// packed fp32 small-param offsets (floats)
#define PB_INIT    0
#define PBSRC_DOWN 128
#define PBDST_DOWN 384
#define PATTN_DOWN 640
#define PBOUT_DOWN 896
#define PBSRC_MID  1152
#define PBDST_MID  1280
#define PATTN_MID  1408
#define PBOUT_MID  1536
#define PBSRC_UP   1664
#define PBDST_UP   1920
#define PATTN_UP   2176
#define PBOUT_UP   2432
#define PB_FIN     2688
#define PARAMS_TOTAL 2816

// split-weight offsets (ushorts, col-major [128][K] per matrix)
#define SP_W_INIT    0        // K=256
#define SP_WSRC_D0   32768    // K=128
#define SP_WSRC_D1   49152
#define SP_WDST_D0   65536
#define SP_WDST_D1   81920
#define SP_WSRC_MID  98304
#define SP_WDST_MID  114688
#define SP_WSRC_U0   131072   // K=256
#define SP_WSRC_U1   163840
#define SP_WDST_U0   196608
#define SP_WDST_U1   229376
#define SP_W_FIN     262144   // K=128
#define SPLIT_TOTAL  278528

extern "C" void kernel_launch(void* const* d_in, const int* in_sizes, int n_in,
                              void* d_out, int out_size, void* d_ws, size_t ws_size,
                              hipStream_t stream) {
  const int N = in_sizes[1] / HIDDIM;
  const int E = in_sizes[2];
  const int* src = (const int*)d_in[2];
  const int* dst = (const int*)d_in[3];

  char* p = (char*)d_ws;
  auto carve = [&](size_t bytes) {
    void* r = (void*)p;
    p += (bytes + 255) & ~(size_t)255;
    return r;
  };
  int* flag     = (int*)carve(256);
  float* params = (float*)carve((size_t)PARAMS_TOTAL * 4);
  unsigned short* whi = (unsigned short*)carve((size_t)SPLIT_TOTAL * 2);
  unsigned short* wlo = (unsigned short*)carve((size_t)SPLIT_TOTAL * 2);
  int* deg      = (int*)carve((size_t)N * 4);
  int* rowptr   = (int*)carve((size_t)(N + 1) * 4);
  int* cursor   = (int*)carve((size_t)N * 4);
  int* bsum     = (int*)carve(1032 * 4);
  int* colsrc   = (int*)carve((size_t)E * 4);
  float* hA     = (float*)carve((size_t)N * HIDDIM * 4);
  float* hB     = (float*)carve((size_t)N * HIDDIM * 4);
  float* hC     = (float*)carve((size_t)N * HIDDIM * 4);
  float* fs     = (float*)carve((size_t)N * HIDDIM * 4);
  float* fd     = (float*)carve((size_t)N * HIDDIM * 4);

  // 1. dtype flag
  detect_dtype<<<1, 256, 0, stream>>>((const unsigned short*)d_in[0], flag);

  // 2. stage small params (biases + attn) in one dispatch
  static const int idx[NITEMS] = {5, 7, 9, 10, 11, 13, 15, 16, 17, 19, 21, 22, 23, 25};
  static const int off[NITEMS] = {
    PB_INIT, PBSRC_DOWN, PBDST_DOWN, PATTN_DOWN, PBOUT_DOWN,
    PBSRC_MID, PBDST_MID, PATTN_MID, PBOUT_MID,
    PBSRC_UP, PBDST_UP, PATTN_UP, PBOUT_UP, PB_FIN};
  static const int cnt[NITEMS] = {
    128, 256, 256, 256, 256, 128, 128, 128, 128, 256, 256, 256, 256, 128};
  StageArgs sa;
  int nb = 0;
  for (int i = 0; i < NITEMS; ++i) {
    sa.src[i] = d_in[idx[i]];
    sa.off[i] = off[i];
    sa.n[i] = cnt[i];
    sa.blk0[i] = nb;
    nb += (cnt[i] + 255) / 256;
  }
  stage_params<<<nb, 256, 0, stream>>>(sa, params, flag);

  // 2b. split weights (direct from inputs) into col-major bf16 hi/lo
  static const int widx[NSPLIT]  = {4, 6, 6, 8, 8, 12, 14, 18, 18, 20, 20, 24};
  static const int weoff[NSPLIT] = {0, 0, 16384, 0, 16384, 0, 0, 0, 32768, 0, 32768, 0};
  static const int wsoff[NSPLIT] = {
    SP_W_INIT, SP_WSRC_D0, SP_WSRC_D1, SP_WDST_D0, SP_WDST_D1,
    SP_WSRC_MID, SP_WDST_MID, SP_WSRC_U0, SP_WSRC_U1, SP_WDST_U0, SP_WDST_U1,
    SP_W_FIN};
  static const int wK[NSPLIT] = {256, 128, 128, 128, 128, 128, 128, 256, 256, 256, 256, 128};
  SplitArgs spa;
  int snb = 0;
  for (int i = 0; i < NSPLIT; ++i) {
    spa.src[i] = d_in[widx[i]];
    spa.eoff[i] = weoff[i];
    spa.soff[i] = wsoff[i];
    spa.K[i] = wK[i];
    spa.blk0[i] = snb;
    snb += (wK[i] * 128 + 255) / 256;
  }
  split_weights<<<snb, 256, 0, stream>>>(spa, whi, wlo, flag);

  // stage x_t, time_embed into fs/fd (consumed by init GEMM before reuse)
  float* xc = fs;
  float* tc = fd;
  cvt_to_f32_2<<<(2 * N * HIDDIM + 255) / 256, 256, 0, stream>>>(
      d_in[0], d_in[1], xc, tc, N * HIDDIM, flag);

  // 3. CSR by dst (multi-block 3-pass scan)
  hipMemsetAsync(deg, 0, (size_t)N * 4, stream);
  count_deg<<<(E + 255) / 256, 256, 0, stream>>>(dst, deg, E);
  int nsb = (N + 1023) / 1024;
  scan_blocks<<<nsb, 1024, 0, stream>>>(deg, rowptr, cursor, bsum, N);
  scan_partials<<<1, 1024, 0, stream>>>(bsum, nsb);
  add_offsets<<<(N + 255) / 256, 256, 0, stream>>>(rowptr, cursor, bsum, N, nsb);
  place_edges<<<(E + 255) / 256, 256, 0, stream>>>(src, dst, cursor, colsrc, E);

  const int nt32 = (N + 31) >> 5;
  dim3 gwy2((unsigned)min(512, nt32), 2);
  dim3 gwy1((unsigned)min(1024, nt32), 1);
  dim3 ga((N + 3) / 4);
  const float* P = params;
  const unsigned short* nh = nullptr;

  // init: hA = gelu([x_t | time_embed] @ W_init + b_init)  (hA kept: skip0)
  gemm_u<8, 1, 1><<<gwy1, 256, 0, stream>>>(
      xc, tc, whi + SP_W_INIT, wlo + SP_W_INIT, nh, nh,
      P + PB_INIT, nullptr, hA, nullptr, N);

  // down 0: hA -> hB   (hB kept: skip1)
  gemm_u<4, 0, 0><<<gwy2, 256, 0, stream>>>(
      hA, nullptr, whi + SP_WSRC_D0, wlo + SP_WSRC_D0, whi + SP_WDST_D0, wlo + SP_WDST_D0,
      P + PBSRC_DOWN, P + PBDST_DOWN, fs, fd, N);
  gat_agg<<<ga, 256, 0, stream>>>(fs, fd, rowptr, colsrc,
                                  P + PATTN_DOWN, P + PBOUT_DOWN, hB, N, E);
  // down 1: hB -> hC
  gemm_u<4, 0, 0><<<gwy2, 256, 0, stream>>>(
      hB, nullptr, whi + SP_WSRC_D1, wlo + SP_WSRC_D1, whi + SP_WDST_D1, wlo + SP_WDST_D1,
      P + PBSRC_DOWN + 128, P + PBDST_DOWN + 128, fs, fd, N);
  gat_agg<<<ga, 256, 0, stream>>>(fs, fd, rowptr, colsrc,
                                  P + PATTN_DOWN + 128, P + PBOUT_DOWN + 128, hC, N, E);
  // mid: hC -> hC
  gemm_u<4, 0, 0><<<gwy2, 256, 0, stream>>>(
      hC, nullptr, whi + SP_WSRC_MID, wlo + SP_WSRC_MID, whi + SP_WDST_MID, wlo + SP_WDST_MID,
      P + PBSRC_MID, P + PBDST_MID, fs, fd, N);
  gat_agg<<<ga, 256, 0, stream>>>(fs, fd, rowptr, colsrc,
                                  P + PATTN_MID, P + PBOUT_MID, hC, N, E);
  // up 0: concat([hC, hB]) -> hC   (single dispatch, K=256, y selects src/dst)
  gemm_u<8, 1, 0><<<gwy2, 256, 0, stream>>>(
      hC, hB, whi + SP_WSRC_U0, wlo + SP_WSRC_U0, whi + SP_WDST_U0, wlo + SP_WDST_U0,
      P + PBSRC_UP, P + PBDST_UP, fs, fd, N);
  gat_agg<<<ga, 256, 0, stream>>>(fs, fd, rowptr, colsrc,
                                  P + PATTN_UP, P + PBOUT_UP, hC, N, E);
  // up 1: concat([hC, hA]) -> hC
  gemm_u<8, 1, 0><<<gwy2, 256, 0, stream>>>(
      hC, hA, whi + SP_WSRC_U1, wlo + SP_WSRC_U1, whi + SP_WDST_U1, wlo + SP_WDST_U1,
      P + PBSRC_UP + 128, P + PBDST_UP + 128, fs, fd, N);
  gat_agg<<<ga, 256, 0, stream>>>(fs, fd, rowptr, colsrc,
                                  P + PATTN_UP + 128, P + PBOUT_UP + 128, hC, N, E);

  // fin: out = hC @ W_fin + b_fin -> hB (dead), then dtype-aware store
  float* outg = hB;
  gemm_u<4, 0, 0><<<gwy1, 256, 0, stream>>>(
      hC, nullptr, whi + SP_W_FIN, wlo + SP_W_FIN, nh, nh,
      P + PB_FIN, nullptr, outg, nullptr, N);
  store_out<<<(N * HIDDIM + 255) / 256, 256, 0, stream>>>(outg, hC, d_out, N * HIDDIM, flag);
}

// Round 10
// 827.447 us; speedup vs baseline: 1.3195x; 1.2051x over previous
//
#include <hip/hip_runtime.h>
#include <hip/hip_bf16.h>
#include <math.h>

#define HIDDIM 128

typedef float f32x4 __attribute__((ext_vector_type(4)));
typedef int i32x4 __attribute__((ext_vector_type(4)));
typedef short bf16x8 __attribute__((ext_vector_type(8)));

__device__ inline float gelu_f(float x) {
  // jax.nn.gelu default approximate=True (tanh form)
  float x3 = x * x * x;
  return 0.5f * x * (1.0f + tanhf(0.7978845608028654f * (x + 0.044715f * x3)));
}

// split fp32 into bf16 hi + bf16 lo (RNE), a ~= hi + lo with ~2^-17 rel err
__device__ inline void split_bf16(float a, unsigned short& hi, unsigned short& lo) {
  unsigned u = __float_as_uint(a);
  unsigned r = (u + 0x7FFFu + ((u >> 16) & 1u)) & 0xFFFF0000u;
  hi = (unsigned short)(r >> 16);
  float rem = a - __uint_as_float(r);  // exact in fp32
  unsigned u2 = __float_as_uint(rem);
  lo = (unsigned short)((u2 + 0x7FFFu + ((u2 >> 16) & 1u)) >> 16);
}

// pair-wise split with packed output: hp = [hi(a1):hi(a0)], lp = [lo(a1):lo(a0)]
__device__ inline void split_pair(float a0, float a1, unsigned& hp, unsigned& lp) {
  unsigned u0 = __float_as_uint(a0), u1 = __float_as_uint(a1);
  unsigned r0 = (u0 + 0x7FFFu + ((u0 >> 16) & 1u)) & 0xFFFF0000u;
  unsigned r1 = (u1 + 0x7FFFu + ((u1 >> 16) & 1u)) & 0xFFFF0000u;
  hp = (r0 >> 16) | r1;
  float m0 = a0 - __uint_as_float(r0);
  float m1 = a1 - __uint_as_float(r1);
  unsigned v0 = __float_as_uint(m0), v1 = __float_as_uint(m1);
  unsigned s0 = v0 + 0x7FFFu + ((v0 >> 16) & 1u);
  unsigned s1 = (v1 + 0x7FFFu + ((v1 >> 16) & 1u)) & 0xFFFF0000u;
  lp = (s0 >> 16) | s1;
}

// split a full 32-float k-chunk fragment (2 float4) into bf16x8 hi/lo
__device__ inline void split_frag(float4 v0, float4 v1, bf16x8& ah, bf16x8& al) {
  i32x4 hv, lv;
  unsigned hp, lp;
  split_pair(v0.x, v0.y, hp, lp); hv[0] = (int)hp; lv[0] = (int)lp;
  split_pair(v0.z, v0.w, hp, lp); hv[1] = (int)hp; lv[1] = (int)lp;
  split_pair(v1.x, v1.y, hp, lp); hv[2] = (int)hp; lv[2] = (int)lp;
  split_pair(v1.z, v1.w, hp, lp); hv[3] = (int)hp; lv[3] = (int)lp;
  ah = __builtin_bit_cast(bf16x8, hv);
  al = __builtin_bit_cast(bf16x8, lv);
}

__device__ inline unsigned short f2bf_rne(float a) {
  unsigned u = __float_as_uint(a);
  return (unsigned short)((u + 0x7FFFu + ((u >> 16) & 1u)) >> 16);
}
__device__ inline float bf2f(unsigned short b) {
  return __uint_as_float((unsigned)b << 16);
}

// Detect whether float tensors are fp32 (flag=1) or bf16 (flag=0).
__global__ void detect_dtype(const unsigned short* __restrict__ raw, int* __restrict__ flag) {
  __shared__ int cnt;
  if (threadIdx.x == 0) cnt = 0;
  __syncthreads();
  int c = 0;
  for (int i = threadIdx.x; i < 8192; i += 256) {
    int ex = (raw[i] >> 7) & 0xFF;
    if (ex >= 0xC0) c++;
  }
  atomicAdd(&cnt, c);
  __syncthreads();
  if (threadIdx.x == 0) flag[0] = (cnt > 64) ? 1 : 0;
}

// fused conversion of x_t and time_embed in one dispatch
__global__ void cvt_to_f32_2(const void* __restrict__ in0, const void* __restrict__ in1,
                             float* __restrict__ out0, float* __restrict__ out1,
                             int n, const int* __restrict__ flag) {
  int i = blockIdx.x * 256 + threadIdx.x;
  if (i < n) {
    out0[i] = flag[0] ? ((const float*)in0)[i]
                      : __bfloat162float(((const __hip_bfloat16*)in0)[i]);
  } else if (i < 2 * n) {
    int j = i - n;
    out1[j] = flag[0] ? ((const float*)in1)[j]
                      : __bfloat162float(((const __hip_bfloat16*)in1)[j]);
  }
}

// ---- small-param staging: biases + attn vectors (14 tensors, one dispatch) ----
#define NITEMS 14
struct StageArgs {
  const void* src[NITEMS];
  int off[NITEMS];    // dest offset in params (floats)
  int n[NITEMS];      // element count
  int blk0[NITEMS];   // first block id of this item
};
__global__ void stage_params(StageArgs a, float* __restrict__ params,
                             const int* __restrict__ flag) {
  int b = blockIdx.x;
  int it = 0;
  while (it + 1 < NITEMS && a.blk0[it + 1] <= b) ++it;
  int i = (b - a.blk0[it]) * 256 + threadIdx.x;
  if (i < a.n[it]) {
    params[a.off[it] + i] = flag[0]
        ? ((const float*)a.src[it])[i]
        : __bfloat162float(((const __hip_bfloat16*)a.src[it])[i]);
  }
}

// ---- split 12 weight matrices (row-major [K][128], fp32 or bf16 input)
// directly from d_in into col-major [128 cols][K] bf16 hi/lo arrays ----
#define NSPLIT 12
struct SplitArgs {
  const void* src[NSPLIT];
  int eoff[NSPLIT];   // element offset within src tensor (layer select)
  int soff[NSPLIT];   // dst offset in whi/wlo (ushorts)
  int K[NSPLIT];
  int blk0[NSPLIT];
};
__global__ void split_weights(SplitArgs a,
                              unsigned short* __restrict__ whi,
                              unsigned short* __restrict__ wlo,
                              const int* __restrict__ flag) {
  int b = blockIdx.x, it = 0;
  while (it + 1 < NSPLIT && a.blk0[it + 1] <= b) ++it;
  int i = (b - a.blk0[it]) * 256 + threadIdx.x;
  int K = a.K[it];
  if (i < K * 128) {
    float v = flag[0]
        ? ((const float*)a.src[it])[a.eoff[it] + i]
        : __bfloat162float(((const __hip_bfloat16*)a.src[it])[a.eoff[it] + i]);
    int k = i >> 7, col = i & 127;
    unsigned short h, lo;
    split_bf16(v, h, lo);
    int o = a.soff[it] + col * K + k;
    whi[o] = h;
    wlo[o] = lo;
  }
}

// ---------------- Unified W-stationary MFMA GEMM ----------
// C[M x 128] = act( A[M x K] @ W + bias ), K = NCH*32 (NCH = 4 or 8).
// TWOSRC: k<128 rows of A from A1, k>=128 from A2 (concat layers / init).
// blockIdx.y selects matrix (W0/b0/C0 vs W1/b1/C1) for fused src/dst layers.
// BF16OUT: matrix 0's output (fs, consumed only by gat_agg's random gather)
// is stored as bf16 -> halves the gather traffic; matrix 1 (fd) stays fp32.
// Wave w covers cols w*32..+32 (CT=2). Grid-stride over 32-row tiles;
// cross-tile 2-deep A pipeline. No LDS, no barriers.
// __launch_bounds__(256,2) is the ONLY non-spilling point (r7/8/9 ladder:
// bound2=116VGPR ok; bound3=84VGPR spill; bound4=64VGPR spill).
// Swapped MFMA operands: D = mfma(W_frag, A_frag) -> lane holds
// C[row = tb*32 + rt*16 + (l&15)][cbase + ct*16 + (l>>4)*4 .. +4].
template <int NCH, int TWOSRC, int ACT, int BF16OUT>
__global__ __launch_bounds__(256, 2) void gemm_u(
    const float* __restrict__ A1, const float* __restrict__ A2,
    const unsigned short* __restrict__ Whi0, const unsigned short* __restrict__ Wlo0,
    const unsigned short* __restrict__ Whi1, const unsigned short* __restrict__ Wlo1,
    const float* __restrict__ b0, const float* __restrict__ b1,
    void* __restrict__ C0, float* __restrict__ C1, int M) {
  constexpr int KS = NCH * 32;
  const int t = threadIdx.x;
  const int w = t >> 6, l = t & 63;
  const int lr = l & 15, lk = l >> 4;
  const int mat = blockIdx.y;
  const unsigned short* whi = mat ? Whi1 : Whi0;
  const unsigned short* wlo = mat ? Wlo1 : Wlo0;
  const float* bw = mat ? b1 : b0;
  const int cbase = w * 32;

  // stationary W fragments
  bf16x8 wh[2][NCH], wl[2][NCH];
#pragma unroll
  for (int ct = 0; ct < 2; ++ct)
#pragma unroll
    for (int s = 0; s < NCH; ++s) {
      size_t off = (size_t)(cbase + ct * 16 + lr) * KS + s * 32 + lk * 8;
      wh[ct][s] = *(const bf16x8*)&whi[off];
      wl[ct][s] = *(const bf16x8*)&wlo[off];
    }
  f32x4 bias[2];
#pragma unroll
  for (int ct = 0; ct < 2; ++ct)
    bias[ct] = *(const f32x4*)&bw[cbase + ct * 16 + lk * 4];

  const int ntiles = (M + 31) >> 5;
  int tb = blockIdx.x;
  int rowc[2];
#pragma unroll
  for (int rt = 0; rt < 2; ++rt) rowc[rt] = min(tb * 32 + rt * 16 + lr, M - 1);

  // prologue: issue chunks 0,1 of first tile (both from A1: NCH>=4)
  float4 rA[2][2][2];  // [buf][rt][q]
#pragma unroll
  for (int s = 0; s < 2; ++s)
#pragma unroll
    for (int rt = 0; rt < 2; ++rt) {
      const float* ap = &A1[(size_t)rowc[rt] * 128 + s * 32 + lk * 8];
      rA[s][rt][0] = *(const float4*)ap;
      rA[s][rt][1] = *(const float4*)(ap + 4);
    }

  for (; tb < ntiles; tb += gridDim.x) {
    const int tn = tb + gridDim.x;
    const bool haveNext = tn < ntiles;
    int rown[2];
#pragma unroll
    for (int rt = 0; rt < 2; ++rt)
      rown[rt] = min((haveNext ? tn : tb) * 32 + rt * 16 + lr, M - 1);

    f32x4 acc[2][2];
#pragma unroll
    for (int rt = 0; rt < 2; ++rt)
#pragma unroll
      for (int ct = 0; ct < 2; ++ct) acc[rt][ct] = (f32x4){0.f, 0.f, 0.f, 0.f};

#pragma unroll
    for (int s = 0; s < NCH; ++s) {
      const int buf = s & 1;
      bf16x8 ah[2], al[2];
#pragma unroll
      for (int rt = 0; rt < 2; ++rt)
        split_frag(rA[buf][rt][0], rA[buf][rt][1], ah[rt], al[rt]);
      // refill buf: s < NCH-2 -> this tile's chunk s+2; else next tile's s-(NCH-2)
      if (s < NCH - 2) {
        const int sn = s + 2;
        const float* Ab = (TWOSRC && sn >= 4) ? A2 : A1;
        const int krel = (sn & 3) * 32 + lk * 8;
#pragma unroll
        for (int rt = 0; rt < 2; ++rt) {
          const float* ap = &Ab[(size_t)rowc[rt] * 128 + krel];
          rA[buf][rt][0] = *(const float4*)ap;
          rA[buf][rt][1] = *(const float4*)(ap + 4);
        }
      } else if (haveNext) {
        const int sn = s - (NCH - 2);
#pragma unroll
        for (int rt = 0; rt < 2; ++rt) {
          const float* ap = &A1[(size_t)rown[rt] * 128 + sn * 32 + lk * 8];
          rA[buf][rt][0] = *(const float4*)ap;
          rA[buf][rt][1] = *(const float4*)(ap + 4);
        }
      }
#pragma unroll
      for (int rt = 0; rt < 2; ++rt)
#pragma unroll
        for (int ct = 0; ct < 2; ++ct) {
          acc[rt][ct] = __builtin_amdgcn_mfma_f32_16x16x32_bf16(wh[ct][s], ah[rt], acc[rt][ct], 0, 0, 0);
          acc[rt][ct] = __builtin_amdgcn_mfma_f32_16x16x32_bf16(wh[ct][s], al[rt], acc[rt][ct], 0, 0, 0);
          acc[rt][ct] = __builtin_amdgcn_mfma_f32_16x16x32_bf16(wl[ct][s], ah[rt], acc[rt][ct], 0, 0, 0);
          // lo*lo dropped: ~2^-18 relative, negligible
        }
    }

    // epilogue: lane covers C[row][cbase + ct*16 + lk*4 .. +4]
#pragma unroll
    for (int rt = 0; rt < 2; ++rt) {
      int r = tb * 32 + rt * 16 + lr;
      if (r < M) {
#pragma unroll
        for (int ct = 0; ct < 2; ++ct) {
          f32x4 v = acc[rt][ct] + bias[ct];
          if (ACT) {
            v[0] = gelu_f(v[0]); v[1] = gelu_f(v[1]);
            v[2] = gelu_f(v[2]); v[3] = gelu_f(v[3]);
          }
          size_t eoff = (size_t)r * 128 + cbase + ct * 16 + lk * 4;
          if (BF16OUT && mat == 0) {
            ushort4 o;
            o.x = f2bf_rne(v[0]); o.y = f2bf_rne(v[1]);
            o.z = f2bf_rne(v[2]); o.w = f2bf_rne(v[3]);
            *(ushort4*)&((unsigned short*)C0)[eoff] = o;
          } else {
            float* cp = mat ? C1 : (float*)C0;
            *(f32x4*)&cp[eoff] = v;
          }
        }
      }
    }
    rowc[0] = rown[0];
    rowc[1] = rown[1];
  }
}

// ---------------- CSR build ----------------
__global__ void count_deg(const int* __restrict__ dst, int* __restrict__ deg, int E) {
  int e = blockIdx.x * 256 + threadIdx.x;
  if (e < E) atomicAdd(&deg[dst[e]], 1);
}

// pass 1: per-block exclusive scan of 1024 elements + block sum
__global__ __launch_bounds__(1024) void scan_blocks(
    const int* __restrict__ deg, int* __restrict__ rowptr,
    int* __restrict__ cursor, int* __restrict__ bsum, int N) {
  __shared__ int buf[1024];
  int i = blockIdx.x * 1024 + threadIdx.x;
  int v = (i < N) ? deg[i] : 0;
  buf[threadIdx.x] = v;
  __syncthreads();
  for (int off = 1; off < 1024; off <<= 1) {
    int add = (threadIdx.x >= (unsigned)off) ? buf[threadIdx.x - off] : 0;
    __syncthreads();
    buf[threadIdx.x] += add;
    __syncthreads();
  }
  int excl = buf[threadIdx.x] - v;
  if (i < N) { rowptr[i] = excl; cursor[i] = excl; }
  if (threadIdx.x == 1023) bsum[blockIdx.x] = buf[1023];
}

// pass 2: single block exclusive-scans the block sums (nb <= 1024)
__global__ __launch_bounds__(1024) void scan_partials(int* __restrict__ bsum, int nb) {
  __shared__ int buf[1024];
  int v = (threadIdx.x < (unsigned)nb) ? bsum[threadIdx.x] : 0;
  buf[threadIdx.x] = v;
  __syncthreads();
  for (int off = 1; off < 1024; off <<= 1) {
    int add = (threadIdx.x >= (unsigned)off) ? buf[threadIdx.x - off] : 0;
    __syncthreads();
    buf[threadIdx.x] += add;
    __syncthreads();
  }
  int excl = buf[threadIdx.x] - v;
  if (threadIdx.x < (unsigned)nb) bsum[threadIdx.x] = excl;
  if (threadIdx.x == 1023) bsum[nb] = buf[1023];  // grand total
}

// pass 3: add block offsets; write rowptr[N]
__global__ void add_offsets(int* __restrict__ rowptr, int* __restrict__ cursor,
                            const int* __restrict__ bsum, int N, int nb) {
  int i = blockIdx.x * 256 + threadIdx.x;
  if (i < N) {
    int add = bsum[i >> 10];
    rowptr[i] += add;
    cursor[i] += add;
  }
  if (i == 0) rowptr[N] = bsum[nb];
}

__global__ void place_edges(const int* __restrict__ src, const int* __restrict__ dst,
                            int* __restrict__ cursor, int* __restrict__ colsrc, int E) {
  int e = blockIdx.x * 256 + threadIdx.x;
  if (e < E) {
    int pos = atomicAdd(&cursor[dst[e]], 1);
    colsrc[pos] = src[e];
  }
}

// ---------------- GATv2 aggregation (bf16 fs gather, x2 edge unroll) -----
// fs is bf16 (written by gemm_u epilogue) -> 256 B/edge gather instead of 512.
// leaky_relu(x)*a == (0.6a)*x + (0.4a)*|x|  (slope 0.2), hoisted coefficients.
__global__ __launch_bounds__(256) void gat_agg(
    const unsigned short* __restrict__ fs, const float* __restrict__ fd,
    const int* __restrict__ rowptr, const int* __restrict__ colsrc,
    const float* __restrict__ attn, const float* __restrict__ bout,
    float* __restrict__ hout, int N, int E) {
  int wv = threadIdx.x >> 6, lane = threadIdx.x & 63;
  int n = blockIdx.x * 4 + wv;
  if (n >= N) return;
  int half = lane >> 5;
  int fb = (lane & 31) * 4;
  float4 fdv = *(const float4*)&fd[(size_t)n * HIDDIM + fb];
  float b0_ = attn[fb], b1_ = attn[fb + 1], b2_ = attn[fb + 2], b3_ = attn[fb + 3];
  float a60 = 0.6f * b0_, a61 = 0.6f * b1_, a62 = 0.6f * b2_, a63 = 0.6f * b3_;
  float a40 = 0.4f * b0_, a41 = 0.4f * b1_, a42 = 0.4f * b2_, a43 = 0.4f * b3_;
  int e0 = rowptr[n], e1 = rowptr[n + 1];
  e0 = max(0, min(e0, E));
  e1 = max(e0, min(e1, E));
  float s = 0.f, ax = 0.f, ay = 0.f, az = 0.f, aw = 0.f;
  for (int c0 = e0; c0 < e1; c0 += 64) {
    int cn = min(64, e1 - c0);
    int myidx = (lane < cn) ? colsrc[c0 + lane] : 0;
    myidx = ((unsigned)myidx < (unsigned)N) ? myidx : 0;
    int iters = (cn + 7) >> 3;
    for (int it = 0; it < iters; ++it) {
      int jb = 8 * it + half;
      int sj[4];
#pragma unroll
      for (int q = 0; q < 4; ++q) sj[q] = __shfl(myidx, jb + 2 * q);
      float4 fj[4];
#pragma unroll
      for (int q = 0; q < 4; ++q) {
        ushort4 u = *(const ushort4*)&fs[(size_t)sj[q] * HIDDIM + fb];
        fj[q] = make_float4(bf2f(u.x), bf2f(u.y), bf2f(u.z), bf2f(u.w));
      }
      float pj[4];
#pragma unroll
      for (int q = 0; q < 4; ++q) {
        float x0 = fj[q].x + fdv.x, x1 = fj[q].y + fdv.y;
        float x2 = fj[q].z + fdv.z, x3 = fj[q].w + fdv.w;
        float lg = fmaf(a60, x0, a40 * fabsf(x0));
        lg = fmaf(a61, x1, fmaf(a41, fabsf(x1), lg));
        lg = fmaf(a62, x2, fmaf(a42, fabsf(x2), lg));
        lg = fmaf(a63, x3, fmaf(a43, fabsf(x3), lg));
        lg += __shfl_xor(lg, 1); lg += __shfl_xor(lg, 2); lg += __shfl_xor(lg, 4);
        lg = fminf(lg, 60.f);
        pj[q] = (jb + 2 * q < cn) ? __expf(lg) : 0.f;
      }
#pragma unroll
      for (int q = 0; q < 4; ++q) {
        s += pj[q];
        ax = fmaf(pj[q], fj[q].x, ax);
        ay = fmaf(pj[q], fj[q].y, ay);
        az = fmaf(pj[q], fj[q].z, az);
        aw = fmaf(pj[q], fj[q].w, aw);
      }
    }
  }
  s += __shfl_xor(s, 32);
  ax += __shfl_xor(ax, 32); ay += __shfl_xor(ay, 32);
  az += __shfl_xor(az, 32); aw += __shfl_xor(aw, 32);
  if (half == 0) {
    float inv = 1.f / (s + 1e-9f);
    float o0 = gelu_f(fmaf(ax, inv, bout[fb]));
    float o1 = gelu_f(fmaf(ay, inv, bout[fb + 1]));
    float o2 = gelu_f(fmaf(az, inv, bout[fb + 2]));
    float o3 = gelu_f(fmaf(aw, inv, bout[fb + 3]));
    *(float4*)&hout[(size_t)n * HIDDIM + fb] = make_float4(o0, o1, o2, o3);
  }
}

__global__ void store_out(const float* __restrict__ og, const float* __restrict__ h,
                          void* __restrict__ dout, int n, const int* __restrict__ flag) {
  int i = blockIdx.x * 256 + threadIdx.x;
  if (i >= n) return;
  if (flag[0]) {
    ((float*)dout)[i] = og[i];
    ((float*)dout)[n + i] = h[i];
  } else {
    ((__hip_bfloat16*)dout)[i] = __float2bfloat16(og[i]);
    ((__hip_bfloat16*)dout)[n + i] = __float2bfloat16(h[i]);
  }
}

// packed fp32 small-param offsets (floats)
#define PB_INIT    0
#define PBSRC_DOWN 128
#define PBDST_DOWN 384
#define PATTN_DOWN 640
#define PBOUT_DOWN 896
#define PBSRC_MID  1152
#define PBDST_MID  1280
#define PATTN_MID  1408
#define PBOUT_MID  1536
#define PBSRC_UP   1664
#define PBDST_UP   1920
#define PATTN_UP   2176
#define PBOUT_UP   2432
#define PB_FIN     2688
#define PARAMS_TOTAL 2816

// split-weight offsets (ushorts, col-major [128][K] per matrix)
#define SP_W_INIT    0        // K=256
#define SP_WSRC_D0   32768    // K=128
#define SP_WSRC_D1   49152
#define SP_WDST_D0   65536
#define SP_WDST_D1   81920
#define SP_WSRC_MID  98304
#define SP_WDST_MID  114688
#define SP_WSRC_U0   131072   // K=256
#define SP_WSRC_U1   163840
#define SP_WDST_U0   196608
#define SP_WDST_U1   229376
#define SP_W_FIN     262144   // K=128
#define SPLIT_TOTAL  278528

extern "C" void kernel_launch(void* const* d_in, const int* in_sizes, int n_in,
                              void* d_out, int out_size, void* d_ws, size_t ws_size,
                              hipStream_t stream) {
  const int N = in_sizes[1] / HIDDIM;
  const int E = in_sizes[2];
  const int* src = (const int*)d_in[2];
  const int* dst = (const int*)d_in[3];

  char* p = (char*)d_ws;
  auto carve = [&](size_t bytes) {
    void* r = (void*)p;
    p += (bytes + 255) & ~(size_t)255;
    return r;
  };
  int* flag     = (int*)carve(256);
  float* params = (float*)carve((size_t)PARAMS_TOTAL * 4);
  unsigned short* whi = (unsigned short*)carve((size_t)SPLIT_TOTAL * 2);
  unsigned short* wlo = (unsigned short*)carve((size_t)SPLIT_TOTAL * 2);
  int* deg      = (int*)carve((size_t)N * 4);
  int* rowptr   = (int*)carve((size_t)(N + 1) * 4);
  int* cursor   = (int*)carve((size_t)N * 4);
  int* bsum     = (int*)carve(1032 * 4);
  int* colsrc   = (int*)carve((size_t)E * 4);
  float* hA     = (float*)carve((size_t)N * HIDDIM * 4);
  float* hB     = (float*)carve((size_t)N * HIDDIM * 4);
  float* hC     = (float*)carve((size_t)N * HIDDIM * 4);
  float* fs     = (float*)carve((size_t)N * HIDDIM * 4);  // bf16 fs / fp32 staging
  float* fd     = (float*)carve((size_t)N * HIDDIM * 4);

  // 1. dtype flag
  detect_dtype<<<1, 256, 0, stream>>>((const unsigned short*)d_in[0], flag);

  // 2. stage small params (biases + attn) in one dispatch
  static const int idx[NITEMS] = {5, 7, 9, 10, 11, 13, 15, 16, 17, 19, 21, 22, 23, 25};
  static const int off[NITEMS] = {
    PB_INIT, PBSRC_DOWN, PBDST_DOWN, PATTN_DOWN, PBOUT_DOWN,
    PBSRC_MID, PBDST_MID, PATTN_MID, PBOUT_MID,
    PBSRC_UP, PBDST_UP, PATTN_UP, PBOUT_UP, PB_FIN};
  static const int cnt[NITEMS] = {
    128, 256, 256, 256, 256, 128, 128, 128, 128, 256, 256, 256, 256, 128};
  StageArgs sa;
  int nb = 0;
  for (int i = 0; i < NITEMS; ++i) {
    sa.src[i] = d_in[idx[i]];
    sa.off[i] = off[i];
    sa.n[i] = cnt[i];
    sa.blk0[i] = nb;
    nb += (cnt[i] + 255) / 256;
  }
  stage_params<<<nb, 256, 0, stream>>>(sa, params, flag);

  // 2b. split weights (direct from inputs) into col-major bf16 hi/lo
  static const int widx[NSPLIT]  = {4, 6, 6, 8, 8, 12, 14, 18, 18, 20, 20, 24};
  static const int weoff[NSPLIT] = {0, 0, 16384, 0, 16384, 0, 0, 0, 32768, 0, 32768, 0};
  static const int wsoff[NSPLIT] = {
    SP_W_INIT, SP_WSRC_D0, SP_WSRC_D1, SP_WDST_D0, SP_WDST_D1,
    SP_WSRC_MID, SP_WDST_MID, SP_WSRC_U0, SP_WSRC_U1, SP_WDST_U0, SP_WDST_U1,
    SP_W_FIN};
  static const int wK[NSPLIT] = {256, 128, 128, 128, 128, 128, 128, 256, 256, 256, 256, 128};
  SplitArgs spa;
  int snb = 0;
  for (int i = 0; i < NSPLIT; ++i) {
    spa.src[i] = d_in[widx[i]];
    spa.eoff[i] = weoff[i];
    spa.soff[i] = wsoff[i];
    spa.K[i] = wK[i];
    spa.blk0[i] = snb;
    snb += (wK[i] * 128 + 255) / 256;
  }
  split_weights<<<snb, 256, 0, stream>>>(spa, whi, wlo, flag);

  // stage x_t, time_embed into fs/fd (fp32; consumed by init GEMM before reuse)
  float* xc = fs;
  float* tc = fd;
  cvt_to_f32_2<<<(2 * N * HIDDIM + 255) / 256, 256, 0, stream>>>(
      d_in[0], d_in[1], xc, tc, N * HIDDIM, flag);

  // 3. CSR by dst (multi-block 3-pass scan)
  hipMemsetAsync(deg, 0, (size_t)N * 4, stream);
  count_deg<<<(E + 255) / 256, 256, 0, stream>>>(dst, deg, E);
  int nsb = (N + 1023) / 1024;
  scan_blocks<<<nsb, 1024, 0, stream>>>(deg, rowptr, cursor, bsum, N);
  scan_partials<<<1, 1024, 0, stream>>>(bsum, nsb);
  add_offsets<<<(N + 255) / 256, 256, 0, stream>>>(rowptr, cursor, bsum, N, nsb);
  place_edges<<<(E + 255) / 256, 256, 0, stream>>>(src, dst, cursor, colsrc, E);

  const int nt32 = (N + 31) >> 5;
  dim3 gwy2((unsigned)min(512, nt32), 2);
  dim3 gwy1((unsigned)min(1024, nt32), 1);
  dim3 ga((N + 3) / 4);
  const float* P = params;
  const unsigned short* nh = nullptr;
  const unsigned short* fsb = (const unsigned short*)fs;

  // init: hA = gelu([x_t | time_embed] @ W_init + b_init)  (hA kept: skip0)
  gemm_u<8, 1, 1, 0><<<gwy1, 256, 0, stream>>>(
      xc, tc, whi + SP_W_INIT, wlo + SP_W_INIT, nh, nh,
      P + PB_INIT, nullptr, hA, nullptr, N);

  // down 0: hA -> hB   (hB kept: skip1)
  gemm_u<4, 0, 0, 1><<<gwy2, 256, 0, stream>>>(
      hA, nullptr, whi + SP_WSRC_D0, wlo + SP_WSRC_D0, whi + SP_WDST_D0, wlo + SP_WDST_D0,
      P + PBSRC_DOWN, P + PBDST_DOWN, fs, fd, N);
  gat_agg<<<ga, 256, 0, stream>>>(fsb, fd, rowptr, colsrc,
                                  P + PATTN_DOWN, P + PBOUT_DOWN, hB, N, E);
  // down 1: hB -> hC
  gemm_u<4, 0, 0, 1><<<gwy2, 256, 0, stream>>>(
      hB, nullptr, whi + SP_WSRC_D1, wlo + SP_WSRC_D1, whi + SP_WDST_D1, wlo + SP_WDST_D1,
      P + PBSRC_DOWN + 128, P + PBDST_DOWN + 128, fs, fd, N);
  gat_agg<<<ga, 256, 0, stream>>>(fsb, fd, rowptr, colsrc,
                                  P + PATTN_DOWN + 128, P + PBOUT_DOWN + 128, hC, N, E);
  // mid: hC -> hC
  gemm_u<4, 0, 0, 1><<<gwy2, 256, 0, stream>>>(
      hC, nullptr, whi + SP_WSRC_MID, wlo + SP_WSRC_MID, whi + SP_WDST_MID, wlo + SP_WDST_MID,
      P + PBSRC_MID, P + PBDST_MID, fs, fd, N);
  gat_agg<<<ga, 256, 0, stream>>>(fsb, fd, rowptr, colsrc,
                                  P + PATTN_MID, P + PBOUT_MID, hC, N, E);
  // up 0: concat([hC, hB]) -> hC   (single dispatch, K=256, y selects src/dst)
  gemm_u<8, 1, 0, 1><<<gwy2, 256, 0, stream>>>(
      hC, hB, whi + SP_WSRC_U0, wlo + SP_WSRC_U0, whi + SP_WDST_U0, wlo + SP_WDST_U0,
      P + PBSRC_UP, P + PBDST_UP, fs, fd, N);
  gat_agg<<<ga, 256, 0, stream>>>(fsb, fd, rowptr, colsrc,
                                  P + PATTN_UP, P + PBOUT_UP, hC, N, E);
  // up 1: concat([hC, hA]) -> hC
  gemm_u<8, 1, 0, 1><<<gwy2, 256, 0, stream>>>(
      hC, hA, whi + SP_WSRC_U1, wlo + SP_WSRC_U1, whi + SP_WDST_U1, wlo + SP_WDST_U1,
      P + PBSRC_UP + 128, P + PBDST_UP + 128, fs, fd, N);
  gat_agg<<<ga, 256, 0, stream>>>(fsb, fd, rowptr, colsrc,
                                  P + PATTN_UP + 128, P + PBOUT_UP + 128, hC, N, E);

  // fin: out = hC @ W_fin + b_fin -> hB (dead), then dtype-aware store
  float* outg = hB;
  gemm_u<4, 0, 0, 0><<<gwy1, 256, 0, stream>>>(
      hC, nullptr, whi + SP_W_FIN, wlo + SP_W_FIN, nh, nh,
      P + PB_FIN, nullptr, outg, nullptr, N);
  store_out<<<(N * HIDDIM + 255) / 256, 256, 0, stream>>>(outg, hC, d_out, N * HIDDIM, flag);
}